// Round 17
// baseline (490.225 us; speedup 1.0000x reference)
//
#include <hip/hip_runtime.h>
#include <hip/hip_bf16.h>
#include <math.h>

#define N_NODES 50000
#define N_EDGES 800000
#define NB      512
#define IN_F    128
#define NH      4
#define HD      64
#define HDIM    256   // NH*HD
#define NG_F    200
#define GH_F    256
#define CSZ     196   // ceil(N_NODES/256)

typedef __attribute__((ext_vector_type(8))) short short8;
typedef __attribute__((ext_vector_type(8))) unsigned short u16x8;
typedef __attribute__((ext_vector_type(4))) float f32x4;
typedef __attribute__((ext_vector_type(2))) float f32x2;

static __device__ __forceinline__ float lrelu(float x){ return x > 0.f ? x : 0.2f*x; }
static __device__ __forceinline__ float fexp(float x){ return __expf(x); }

static __device__ __forceinline__ unsigned short f2b(float f){
  union { float f; unsigned int u; } v; v.f = f;
  unsigned int r = v.u + 0x7fffu + ((v.u >> 16) & 1u);
  return (unsigned short)(r >> 16);
}
static __device__ __forceinline__ float b2f(unsigned short b){
  union { unsigned int u; float f; } v; v.u = ((unsigned int)b) << 16;
  return v.f;
}
static __device__ __forceinline__ float u2f(unsigned int u){
  union { unsigned int u; float f; } v; v.u = u;
  return v.f;
}

// ---------------- fp32 -> bf16 conversion (n % 4 == 0) ----------------
__global__ __launch_bounds__(256) void k_f2b(const float* __restrict__ in, unsigned short* __restrict__ out, int n4){
  int i = blockIdx.x*256 + threadIdx.x;
  if (i >= n4) return;
  float4 v = ((const float4*)in)[i];
  ushort4 o;
  o.x = f2b(v.x); o.y = f2b(v.y); o.z = f2b(v.z); o.w = f2b(v.w);
  ((ushort4*)out)[i] = o;
}

// ---------------- g_feat [NB][NG_F] -> bf16 zero-padded [NB][256] ----------------
__global__ __launch_bounds__(256) void k_padg(const float* __restrict__ g, unsigned short* __restrict__ out){
  int idx = blockIdx.x*256 + threadIdx.x;   // NB*256
  if (idx >= NB*256) return;
  int b = idx >> 8, k = idx & 255;
  out[idx] = (k < NG_F) ? f2b(g[b*NG_F + k]) : (unsigned short)0;
}

// ---------------- fp32 W[Ksrc][NC] -> bf16 W^T[NC][Kdst], zero-padded rows ----------------
__global__ __launch_bounds__(256) void k_w2bt(const float* __restrict__ W, unsigned short* __restrict__ Bt,
                                              int Ksrc, int Kdst, int NC){
  __shared__ unsigned short t[32][33];
  int bn = blockIdx.x*32;   // NC tile
  int bk = blockIdx.y*32;   // K tile
  int lx = threadIdx.x & 31, ly = threadIdx.x >> 5;   // 32 x 8
  #pragma unroll
  for (int i = 0; i < 32; i += 8) {
    int kr = bk + ly + i;
    t[ly+i][lx] = (kr < Ksrc) ? f2b(W[(size_t)kr*NC + bn+lx]) : (unsigned short)0;
  }
  __syncthreads();
  #pragma unroll
  for (int i = 0; i < 32; i += 8)
    Bt[(size_t)(bn+ly+i)*Kdst + bk+lx] = t[lx][ly+i];
}

// ---------------- CSR build ----------------
__global__ __launch_bounds__(256) void k_hist(const int* __restrict__ dst, int* __restrict__ deg){
  int e = blockIdx.x*256 + threadIdx.x;
  if (e < N_EDGES) atomicAdd(&deg[dst[e]], 1);
}

// stage 1: per-chunk sums (256 blocks x 64 lanes, coalesced)
__global__ __launch_bounds__(64) void k_s1a(const int* __restrict__ deg, int* __restrict__ blocksum){
  int b = blockIdx.x, lane = threadIdx.x;
  int start = b*CSZ, end = min(start+CSZ, N_NODES);
  int s = 0;
  for (int i = start + lane; i < end; i += 64) s += deg[i];
  #pragma unroll
  for (int m = 1; m < 64; m <<= 1) s += __shfl_xor(s, m);
  if (lane == 0) blocksum[b] = s;
}

// stage 2: exclusive scan of the 256 chunk sums
__global__ __launch_bounds__(256) void k_s1b(const int* __restrict__ blocksum, int* __restrict__ chunkoff){
  __shared__ int sd[256];
  int t = threadIdx.x;
  int own = blocksum[t];
  sd[t] = own; __syncthreads();
  for (int off = 1; off < 256; off <<= 1) {
    int v = (t >= off) ? sd[t-off] : 0;
    __syncthreads();
    sd[t] += v;
    __syncthreads();
  }
  chunkoff[t] = sd[t] - own;
}

// stage 3: per-chunk prefix via wave scan
__global__ __launch_bounds__(64) void k_scan2(const int* __restrict__ deg, const int* __restrict__ chunkoff,
                                              int* __restrict__ row_start, int* __restrict__ cursor){
  int b = blockIdx.x, lane = threadIdx.x;
  int start = b*CSZ, end = min(start+CSZ, N_NODES);
  int run = chunkoff[b];
  for (int k = start; k < end; k += 64) {
    int idx = k + lane;
    int v = (idx < end) ? deg[idx] : 0;
    int inc = v;
    #pragma unroll
    for (int off = 1; off < 64; off <<= 1) {
      int t = __shfl_up(inc, off);
      if (lane >= off) inc += t;
    }
    int excl = run + inc - v;
    if (idx < end) { row_start[idx] = excl; cursor[idx] = excl; }
    run += __shfl(inc, 63);
  }
  if (b == 255 && lane == 0) row_start[N_NODES] = run;
}

// store src node id directly (coalesced read later)
__global__ __launch_bounds__(256) void k_scatter(const int* __restrict__ dst, const int* __restrict__ src,
                                                 int* __restrict__ cursor, int* __restrict__ csrc){
  int e = blockIdx.x*256 + threadIdx.x;
  if (e < N_EDGES) {
    int p = atomicAdd(&cursor[dst[e]], 1);
    csrc[p] = src[e];
  }
}

// ---------------- graph segment offsets from sorted gid ----------------
__global__ __launch_bounds__(256) void k_goff(const int* __restrict__ gid, int* __restrict__ goff){
  int n = blockIdx.x*256 + threadIdx.x;
  if (n >= N_NODES) return;
  int ca = gid[n];
  if (n == 0) {
    for (int g = 0; g <= ca; g++) goff[g] = 0;
  } else {
    int pa = gid[n-1];
    for (int g = pa+1; g <= ca; g++) goff[g] = n;
  }
  if (n == N_NODES-1) {
    for (int g = ca+1; g <= NB; g++) goff[g] = N_NODES;
  }
}

// ---------------- bf16 MFMA GEMM with XCD-aware 1D grid ----------------
__global__ __launch_bounds__(256) void k_gemm_bf16(const unsigned short* __restrict__ A,
                                                   const unsigned short* __restrict__ Bt,
                                                   unsigned short* __restrict__ C,
                                                   const float* __restrict__ bias, int act,
                                                   const float* __restrict__ al, const float* __restrict__ ar,
                                                   float* __restrict__ el, float* __restrict__ er,
                                                   int M, int K, int NC, int ntiles){
  __shared__ unsigned short As[128][72];
  __shared__ unsigned short Bs[64][72];
  __shared__ float sEL[2][2][4][16];
  __shared__ float sER[2][2][4][16];
  const int bid = blockIdx.x;
  const int xcd = bid & 7;
  const int r   = bid >> 3;
  const int q   = r / ntiles;
  const int nt  = r - q*ntiles;
  const int mtile = q*8 + xcd;
  if (mtile*128 >= M) return;
  const int bm = mtile*128, bn = nt*64;
  const int tid = threadIdx.x;
  const int wid = tid >> 6, lane = tid & 63;
  const int wr = wid >> 1, wc = wid & 1;
  const int l15 = lane & 15, lg = lane >> 4;
  const int ar_ = tid >> 1, ak = (tid & 1) * 32;
  const int br = tid >> 2, bkp = (tid & 3) * 16;
  int agrow = bm + ar_; if (agrow >= M) agrow = M - 1;

  f32x4 acc[4][2] = {};
  for (int k0 = 0; k0 < K; k0 += 64) {
    #pragma unroll
    for (int p = 0; p < 4; p++)
      *(uint4*)(&As[ar_][ak + p*8]) = *(const uint4*)(A + (size_t)agrow*K + k0 + ak + p*8);
    #pragma unroll
    for (int p = 0; p < 2; p++)
      *(uint4*)(&Bs[br][bkp + p*8]) = *(const uint4*)(Bt + (size_t)(bn + br)*K + k0 + bkp + p*8);
    __syncthreads();
    #pragma unroll
    for (int ks = 0; ks < 2; ks++) {
      short8 af[4], bf[2];
      #pragma unroll
      for (int m = 0; m < 4; m++) af[m] = *(const short8*)(&As[wr*64 + m*16 + l15][ks*32 + lg*8]);
      #pragma unroll
      for (int nn = 0; nn < 2; nn++) bf[nn] = *(const short8*)(&Bs[wc*32 + nn*16 + l15][ks*32 + lg*8]);
      #pragma unroll
      for (int m = 0; m < 4; m++)
        #pragma unroll
        for (int nn = 0; nn < 2; nn++)
          acc[m][nn] = __builtin_amdgcn_mfma_f32_16x16x32_bf16(af[m], bf[nn], acc[m][nn], 0, 0, 0);
    }
    __syncthreads();
  }
  #pragma unroll
  for (int m = 0; m < 4; m++)
    #pragma unroll
    for (int nn = 0; nn < 2; nn++) {
      int col = bn + wc*32 + nn*16 + l15;
      float bv = bias ? bias[col] : 0.f;
      #pragma unroll
      for (int i = 0; i < 4; i++) {
        int row = bm + wr*64 + m*16 + lg*4 + i;
        if (row < M) {
          float v = acc[m][nn][i] + bv;
          if (act) v = fmaxf(v, 0.f);
          C[(size_t)row*NC + col] = f2b(v);
        }
      }
    }
  // fused attention-logit epilogue
  if (al) {
    int hidx = bn >> 6;
    float pl[16], pr[16];
    #pragma unroll
    for (int m = 0; m < 4; m++)
      #pragma unroll
      for (int i = 0; i < 4; i++) {
        float sl = 0.f, sr = 0.f;
        #pragma unroll
        for (int nn = 0; nn < 2; nn++) {
          int colh = wc*32 + nn*16 + l15;
          sl += acc[m][nn][i] * al[hidx*64 + colh];
          sr += acc[m][nn][i] * ar[hidx*64 + colh];
        }
        pl[m*4+i] = sl; pr[m*4+i] = sr;
      }
    #pragma unroll
    for (int k = 0; k < 16; k++) {
      #pragma unroll
      for (int mm = 1; mm < 16; mm <<= 1) {
        pl[k] += __shfl_xor(pl[k], mm);
        pr[k] += __shfl_xor(pr[k], mm);
      }
    }
    if (l15 == 0) {
      #pragma unroll
      for (int k = 0; k < 16; k++) { sEL[wr][wc][lg][k] = pl[k]; sER[wr][wc][lg][k] = pr[k]; }
    }
    __syncthreads();
    if (tid < 128) {
      int k = tid & 15;
      int lg2 = (tid >> 4) & 3;
      int wr2 = tid >> 6;
      float vl = sEL[wr2][0][lg2][k] + sEL[wr2][1][lg2][k];
      float vr = sER[wr2][0][lg2][k] + sER[wr2][1][lg2][k];
      int m = k >> 2, i = k & 3;
      int row = bm + wr2*64 + m*16 + lg2*4 + i;
      if (row < M) { el[row*NH + hidx] = vl; er[row*NH + hidx] = vr; }
    }
  }
}

// ---------------- fused edge softmax + aggregation, feature-split + XCD-pinned ----------------
// Grid: 8 * (N_NODES/16). bid decode: xcd=bid&7, half=xcd>>2 (features half*128..+127),
// sub=xcd&3, node_block = (bid>>3)*4 + sub (4 nodes each). Each XCD touches only half the
// feature columns -> per-XCD L2 working set 12.8 MB (was 25.6), total L2-fill halved.
// Per wave: 1 node, 4 edges x 16 lanes x 16B; 4 supersteps in flight (depth-4 proven).
__global__ __launch_bounds__(256) void k_agg(
    const unsigned short* __restrict__ f, const float* __restrict__ el, const float* __restrict__ er,
    const int* __restrict__ row_start, const int* __restrict__ csrc,
    const unsigned short* __restrict__ resid, unsigned short* __restrict__ out, int act){
  __shared__ float sA[4][64][4];
  __shared__ int   sS[4][64];
  int bid  = blockIdx.x;
  int xcd  = bid & 7;
  int half = xcd >> 2;                 // feature half 0/1
  int sub  = xcd & 3;
  int nblk = (bid >> 3)*4 + sub;       // node block 0..12499
  int wid  = threadIdx.x >> 6;
  int lane = threadIdx.x & 63;
  int n = nblk*4 + wid;                // N_NODES = 4*12500
  int eq = lane >> 4;                  // edge-in-quad 0..3
  int fl = lane & 15;                  // feature slot within half
  int fc = half*16 + fl;               // 16B-column index 0..31
  int h  = fc >> 3;                    // head of this column
  int e0 = row_start[n], e1 = row_start[n+1];
  float4 erv = ((const float4*)er)[n];

  float4 den = make_float4(0.f,0.f,0.f,0.f);
  f32x2 acc2[4] = {};

  for (int base = e0; base < e1; base += 64) {
    int cnt = min(64, e1 - base);
    int   s_l = 0;
    float4 a4 = make_float4(0.f,0.f,0.f,0.f);
    if (base + lane < e1) {
      s_l = csrc[base + lane];
      float4 ev = ((const float4*)el)[s_l];
      a4.x = fexp(lrelu(ev.x + erv.x));
      a4.y = fexp(lrelu(ev.y + erv.y));
      a4.z = fexp(lrelu(ev.z + erv.z));
      a4.w = fexp(lrelu(ev.w + erv.w));
    }
    den.x += a4.x; den.y += a4.y; den.z += a4.z; den.w += a4.w;
    sS[wid][lane] = s_l;
    sA[wid][lane][0] = a4.x; sA[wid][lane][1] = a4.y;
    sA[wid][lane][2] = a4.z; sA[wid][lane][3] = a4.w;
    __builtin_amdgcn_sched_barrier(0);   // ds_writes complete before the read loop (intra-wave in-order)
    for (int j = 0; j < cnt; j += 16) {  // 16 edges = 4 quads per superstep (4 loads in flight/lane)
      uint4 u[4]; f32x2 aa[4];
      #pragma unroll
      for (int p = 0; p < 4; p++) {
        int jj = j + 4*p + eq;
        float a = 0.f; int s;
        if (jj < cnt) { s = sS[wid][jj]; a = sA[wid][jj][h]; } else { s = sS[wid][j]; }
        u[p] = *(const uint4*)(f + (size_t)s*HDIM + fc*8);
        aa[p][0] = a; aa[p][1] = a;
      }
      #pragma unroll
      for (int p = 0; p < 4; p++) {
        f32x2 p0, p1, p2, p3;
        p0[0] = u2f(u[p].x << 16); p0[1] = u2f(u[p].x & 0xffff0000u);
        p1[0] = u2f(u[p].y << 16); p1[1] = u2f(u[p].y & 0xffff0000u);
        p2[0] = u2f(u[p].z << 16); p2[1] = u2f(u[p].z & 0xffff0000u);
        p3[0] = u2f(u[p].w << 16); p3[1] = u2f(u[p].w & 0xffff0000u);
        asm volatile("v_pk_fma_f32 %0, %1, %2, %0" : "+v"(acc2[0]) : "v"(p0), "v"(aa[p]));
        asm volatile("v_pk_fma_f32 %0, %1, %2, %0" : "+v"(acc2[1]) : "v"(p1), "v"(aa[p]));
        asm volatile("v_pk_fma_f32 %0, %1, %2, %0" : "+v"(acc2[2]) : "v"(p2), "v"(aa[p]));
        asm volatile("v_pk_fma_f32 %0, %1, %2, %0" : "+v"(acc2[3]) : "v"(p3), "v"(aa[p]));
      }
    }
  }
  // reduce den across wave (each lane accumulated a disjoint edge subset)
  #pragma unroll
  for (int m = 1; m < 64; m <<= 1) {
    den.x += __shfl_xor(den.x, m);
    den.y += __shfl_xor(den.y, m);
    den.z += __shfl_xor(den.z, m);
    den.w += __shfl_xor(den.w, m);
  }
  // merge quads: lanes {fl, fl+16, fl+32, fl+48} hold partials of the same column
  float accv[8];
  #pragma unroll
  for (int q = 0; q < 4; q++) {
    float v0 = acc2[q][0], v1 = acc2[q][1];
    v0 += __shfl_xor(v0, 16); v0 += __shfl_xor(v0, 32);
    v1 += __shfl_xor(v1, 16); v1 += __shfl_xor(v1, 32);
    accv[2*q] = v0; accv[2*q+1] = v1;
  }

  float d_h = h==0 ? den.x : h==1 ? den.y : h==2 ? den.z : den.w;
  float inv = d_h > 0.f ? 1.0f/d_h : 0.f;

  if (eq == 0) {
    #pragma unroll
    for (int k = 0; k < 8; k++) accv[k] *= inv;
    if (resid) {
      u16x8 r = *(const u16x8*)(resid + (size_t)n*HDIM + fc*8);
      #pragma unroll
      for (int k = 0; k < 8; k++) accv[k] += b2f((unsigned short)r[k]);
    }
    if (act) {
      #pragma unroll
      for (int k = 0; k < 8; k++) accv[k] = accv[k] > 0.f ? accv[k] : (fexp(accv[k]) - 1.0f);
    }
    u16x8 o;
    #pragma unroll
    for (int k = 0; k < 8; k++) o[k] = f2b(accv[k]);
    *(u16x8*)(out + (size_t)n*HDIM + fc*8) = o;
  }
}

// ---------------- layer 3 projection from bf16 h ----------------
__global__ __launch_bounds__(256) void k_l3proj(const unsigned short* __restrict__ h,
    const float* __restrict__ W3, const float* __restrict__ rW3,
    const float* __restrict__ al3, const float* __restrict__ ar3,
    float* __restrict__ f3, float* __restrict__ r3,
    float* __restrict__ el3, float* __restrict__ er3){
  int n = blockIdx.x*4 + (threadIdx.x >> 6);
  int lane = threadIdx.x & 63;
  if (n >= N_NODES) return;
  ushort4 u = ((const ushort4*)(h + (size_t)n*HDIM))[lane];
  float hk[4] = {b2f(u.x), b2f(u.y), b2f(u.z), b2f(u.w)};
  const float4* w  = (const float4*)W3;
  const float4* rw = (const float4*)rW3;
  float4 acc = make_float4(0.f,0.f,0.f,0.f);
  float4 rac = make_float4(0.f,0.f,0.f,0.f);
  #pragma unroll
  for (int j = 0; j < 4; j++) {
    float4 wv = w[lane*4 + j];
    float4 rv = rw[lane*4 + j];
    acc.x += hk[j]*wv.x; acc.y += hk[j]*wv.y; acc.z += hk[j]*wv.z; acc.w += hk[j]*wv.w;
    rac.x += hk[j]*rv.x; rac.y += hk[j]*rv.y; rac.z += hk[j]*rv.z; rac.w += hk[j]*rv.w;
  }
  #pragma unroll
  for (int m = 1; m < 64; m <<= 1) {
    acc.x += __shfl_xor(acc.x, m); acc.y += __shfl_xor(acc.y, m);
    acc.z += __shfl_xor(acc.z, m); acc.w += __shfl_xor(acc.w, m);
    rac.x += __shfl_xor(rac.x, m); rac.y += __shfl_xor(rac.y, m);
    rac.z += __shfl_xor(rac.z, m); rac.w += __shfl_xor(rac.w, m);
  }
  if (lane == 0) {
    ((float4*)f3)[n] = acc;
    ((float4*)r3)[n] = rac;
    float4 e1 = make_float4(acc.x*al3[0], acc.y*al3[1], acc.z*al3[2], acc.w*al3[3]);
    float4 e2 = make_float4(acc.x*ar3[0], acc.y*ar3[1], acc.z*ar3[2], acc.w*ar3[3]);
    ((float4*)el3)[n] = e1;
    ((float4*)er3)[n] = e2;
  }
}

// ---------------- layer 3 per-node aggregation -> hn[N][4] (NO atomics) ----------------
__global__ __launch_bounds__(256) void k_l3node(
    const float* __restrict__ f3, const float* __restrict__ el3, const float* __restrict__ er3,
    const int* __restrict__ row_start, const int* __restrict__ csrc,
    const float* __restrict__ r3, float* __restrict__ hn){
  int g = threadIdx.x >> 4;
  int l = threadIdx.x & 15;
  int n = blockIdx.x*16 + g;        // N_NODES % 16 == 0
  int e0 = row_start[n], e1 = row_start[n+1];
  float4 erv = ((const float4*)er3)[n];

  float4 dn  = make_float4(0.f,0.f,0.f,0.f);
  float4 acc = make_float4(0.f,0.f,0.f,0.f);
  for (int i = e0 + l; i < e1; i += 16) {
    int s = csrc[i];
    float4 ev = ((const float4*)el3)[s];
    float ax = fexp(lrelu(ev.x + erv.x));
    float ay = fexp(lrelu(ev.y + erv.y));
    float az = fexp(lrelu(ev.z + erv.z));
    float aw = fexp(lrelu(ev.w + erv.w));
    dn.x += ax; dn.y += ay; dn.z += az; dn.w += aw;
    float4 fv = ((const float4*)f3)[s];
    acc.x += ax*fv.x; acc.y += ay*fv.y; acc.z += az*fv.z; acc.w += aw*fv.w;
  }
  #pragma unroll
  for (int m = 1; m < 16; m <<= 1) {
    dn.x += __shfl_xor(dn.x, m);  dn.y += __shfl_xor(dn.y, m);
    dn.z += __shfl_xor(dn.z, m);  dn.w += __shfl_xor(dn.w, m);
    acc.x += __shfl_xor(acc.x, m); acc.y += __shfl_xor(acc.y, m);
    acc.z += __shfl_xor(acc.z, m); acc.w += __shfl_xor(acc.w, m);
  }
  if (l == 0) {
    float4 rv = ((const float4*)r3)[n];
    float4 o;
    o.x = (dn.x > 0.f ? acc.x/dn.x : 0.f) + rv.x;
    o.y = (dn.y > 0.f ? acc.y/dn.y : 0.f) + rv.y;
    o.z = (dn.z > 0.f ? acc.z/dn.z : 0.f) + rv.z;
    o.w = (dn.w > 0.f ? acc.w/dn.w : 0.f) + rv.w;
    ((float4*)hn)[n] = o;
  }
}

// ---------------- deterministic per-graph segment sum ----------------
__global__ __launch_bounds__(64) void k_gseg(const float* __restrict__ hn, const int* __restrict__ goff,
                                             float* __restrict__ latent){
  int b = blockIdx.x;
  int lane = threadIdx.x;
  int n0 = goff[b], n1 = goff[b+1];
  float4 s = make_float4(0.f,0.f,0.f,0.f);
  for (int n = n0 + lane; n < n1; n += 64) {
    float4 v = ((const float4*)hn)[n];
    s.x += v.x; s.y += v.y; s.z += v.z; s.w += v.w;
  }
  #pragma unroll
  for (int m = 1; m < 64; m <<= 1) {
    s.x += __shfl_xor(s.x, m); s.y += __shfl_xor(s.y, m);
    s.z += __shfl_xor(s.z, m); s.w += __shfl_xor(s.w, m);
  }
  if (lane == 0) ((float4*)latent)[b] = s;
}

// ---------------- final ----------------
__global__ __launch_bounds__(256) void k_final(const float* __restrict__ latent, const unsigned short* __restrict__ lgb,
    const float* __restrict__ lw, const float* __restrict__ lb, float* __restrict__ out){
  int b = blockIdx.x*4 + (threadIdx.x >> 6);
  int lane = threadIdx.x & 63;
  if (b >= NB) return;
  ushort4 u = ((const ushort4*)(lgb + (size_t)b*GH_F))[lane];
  float4 wv = ((const float4*)(lw + NH))[lane];
  float s = b2f(u.x)*wv.x + b2f(u.y)*wv.y + b2f(u.z)*wv.z + b2f(u.w)*wv.w;
  #pragma unroll
  for (int m = 1; m < 64; m <<= 1) s += __shfl_xor(s, m);
  if (lane == 0) {
    float4 lv = ((const float4*)latent)[b];
    out[b] = s + lv.x*lw[0] + lv.y*lw[1] + lv.z*lw[2] + lv.w*lw[3] + lb[0];
  }
}

__global__ __launch_bounds__(256) void k_sentinel(float* out){
  int i = blockIdx.x*256 + threadIdx.x;
  if (i < NB) out[i] = -12345.0f;
}

extern "C" void kernel_launch(void* const* d_in, const int* in_sizes, int n_in,
                              void* d_out, int out_size, void* d_ws, size_t ws_size,
                              hipStream_t stream){
  const float* feat   = (const float*)d_in[0];
  const int*   src    = (const int*)d_in[1];
  const int*   dst    = (const int*)d_in[2];
  const int*   gid    = (const int*)d_in[3];
  const float* g_feat = (const float*)d_in[4];
  const float* W0   = (const float*)d_in[5];
  const float* al0  = (const float*)d_in[6];
  const float* ar0  = (const float*)d_in[7];
  const float* W1   = (const float*)d_in[8];
  const float* al1  = (const float*)d_in[9];
  const float* ar1  = (const float*)d_in[10];
  const float* W2   = (const float*)d_in[11];
  const float* al2  = (const float*)d_in[12];
  const float* ar2  = (const float*)d_in[13];
  const float* W3   = (const float*)d_in[14];
  const float* al3  = (const float*)d_in[15];
  const float* ar3  = (const float*)d_in[16];
  const float* rW3  = (const float*)d_in[17];
  const float* gw1  = (const float*)d_in[18];
  const float* gb1  = (const float*)d_in[19];
  const float* gw2  = (const float*)d_in[20];
  const float* gb2  = (const float*)d_in[21];
  const float* lw   = (const float*)d_in[22];
  const float* lb   = (const float*)d_in[23];
  float* out = (float*)d_out;

  char* base = (char*)d_ws;
  size_t off = 0;
  auto alloc = [&](size_t bytes)->char* {
    char* r = base + off;
    off += (bytes + 255) & ~(size_t)255;
    return r;
  };
  // bf16 buffers
  unsigned short* featb = (unsigned short*)alloc((size_t)N_NODES*IN_F*2);
  unsigned short* fbuf  = (unsigned short*)alloc((size_t)N_NODES*HDIM*2);
  unsigned short* hA    = (unsigned short*)alloc((size_t)N_NODES*HDIM*2);
  unsigned short* hB    = (unsigned short*)alloc((size_t)N_NODES*HDIM*2);
  unsigned short* W0t   = (unsigned short*)alloc((size_t)IN_F*HDIM*2);   // [HDIM][IN_F]
  unsigned short* W1t   = (unsigned short*)alloc((size_t)HDIM*HDIM*2);
  unsigned short* W2t   = (unsigned short*)alloc((size_t)HDIM*HDIM*2);
  unsigned short* gfb   = (unsigned short*)alloc((size_t)NB*256*2);      // padded g_feat
  unsigned short* gw1t  = (unsigned short*)alloc((size_t)GH_F*256*2);    // [256][256] (K padded)
  unsigned short* gw2t  = (unsigned short*)alloc((size_t)GH_F*GH_F*2);
  unsigned short* g1b   = (unsigned short*)alloc((size_t)NB*GH_F*2);
  unsigned short* lgb   = (unsigned short*)alloc((size_t)NB*GH_F*2);
  // fp32 small buffers
  float* el   = (float*)alloc((size_t)N_NODES*NH*4);
  float* er   = (float*)alloc((size_t)N_NODES*NH*4);
  float* f3   = (float*)alloc((size_t)N_NODES*NH*4);
  float* r3   = (float*)alloc((size_t)N_NODES*NH*4);
  float* hn   = (float*)alloc((size_t)N_NODES*NH*4);
  int* deg       = (int*)alloc((size_t)N_NODES*4);
  int* row_start = (int*)alloc((size_t)(N_NODES+1)*4);
  int* cursor    = (int*)alloc((size_t)N_NODES*4);
  int* csrc      = (int*)alloc((size_t)N_EDGES*4);
  int* blocksum  = (int*)alloc(256*4);
  int* chunkoff  = (int*)alloc(256*4);
  int* goff      = (int*)alloc((size_t)(NB+1)*4);
  float* latent  = (float*)alloc((size_t)NB*NH*4);

  if (off > ws_size) {
    k_sentinel<<<2, 256, 0, stream>>>(out);
    return;
  }

  // conversions: feat -> bf16; weights -> bf16 transposed [NC][K]
  k_f2b<<<((N_NODES*IN_F/4)+255)/256, 256, 0, stream>>>(feat, featb, N_NODES*IN_F/4);
  {
    dim3 g0(HDIM/32, IN_F/32), g12(HDIM/32, HDIM/32), gm(256/32, 256/32);
    k_w2bt<<<g0, 256, 0, stream>>>(W0, W0t, IN_F, IN_F, HDIM);
    k_w2bt<<<g12, 256, 0, stream>>>(W1, W1t, HDIM, HDIM, HDIM);
    k_w2bt<<<g12, 256, 0, stream>>>(W2, W2t, HDIM, HDIM, HDIM);
    k_w2bt<<<gm, 256, 0, stream>>>(gw1, gw1t, NG_F, 256, GH_F);    // zero-padded K 200->256
    k_w2bt<<<gm, 256, 0, stream>>>(gw2, gw2t, GH_F, GH_F, GH_F);
  }
  k_padg<<<(NB*256+255)/256, 256, 0, stream>>>(g_feat, gfb);

  // CSR build (shared by all 4 layers) + graph offsets — parallel 3-stage scan
  hipMemsetAsync(deg, 0, (size_t)N_NODES*4, stream);
  k_hist<<<(N_EDGES+255)/256, 256, 0, stream>>>(dst, deg);
  k_s1a<<<256, 64, 0, stream>>>(deg, blocksum);
  k_s1b<<<1, 256, 0, stream>>>(blocksum, chunkoff);
  k_scan2<<<256, 64, 0, stream>>>(deg, chunkoff, row_start, cursor);
  k_scatter<<<(N_EDGES+255)/256, 256, 0, stream>>>(dst, src, cursor, csrc);
  k_goff<<<(N_NODES+255)/256, 256, 0, stream>>>(gid, goff);

  // XCD-aware 1D grids
  const int mt_main = (N_NODES + 127) / 128;                 // 391
  const int grid_main = 8 * ((mt_main + 7) / 8) * 4;         // 1568
  const int mt_mlp = (NB + 127) / 128;                       // 4
  const int grid_mlp = 8 * ((mt_mlp + 7) / 8) * 4;           // 32
  const int grid_agg = 8 * (N_NODES / 16);                   // 25000 (2 halves x 12500 node-blocks)

  // Layer 0 (GEMM with fused logits)
  k_gemm_bf16<<<grid_main, 256, 0, stream>>>(featb, W0t, fbuf, nullptr, 0, al0, ar0, el, er, N_NODES, IN_F, HDIM, 4);
  k_agg<<<grid_agg, 256, 0, stream>>>(fbuf, el, er, row_start, csrc, nullptr, hA, 1);

  // Layer 1
  k_gemm_bf16<<<grid_main, 256, 0, stream>>>(hA, W1t, fbuf, nullptr, 0, al1, ar1, el, er, N_NODES, HDIM, HDIM, 4);
  k_agg<<<grid_agg, 256, 0, stream>>>(fbuf, el, er, row_start, csrc, hA, hB, 1);

  // Layer 2
  k_gemm_bf16<<<grid_main, 256, 0, stream>>>(hB, W2t, fbuf, nullptr, 0, al2, ar2, el, er, N_NODES, HDIM, HDIM, 4);
  k_agg<<<grid_agg, 256, 0, stream>>>(fbuf, el, er, row_start, csrc, hB, hA, 1);

  // Layer 3 (C=1): per-node output then deterministic per-graph segment sum
  k_l3proj<<<(N_NODES+3)/4, 256, 0, stream>>>(hA, W3, rW3, al3, ar3, f3, r3, el, er);
  k_l3node<<<N_NODES/16, 256, 0, stream>>>(f3, el, er, row_start, csrc, r3, hn);
  k_gseg<<<NB, 64, 0, stream>>>(hn, goff, latent);

  // Graph MLP via MFMA GEMM (K padded to 256) + final
  k_gemm_bf16<<<grid_mlp, 256, 0, stream>>>(gfb, gw1t, g1b, gb1, 1, nullptr, nullptr, nullptr, nullptr, NB, 256, GH_F, 4);
  k_gemm_bf16<<<grid_mlp, 256, 0, stream>>>(g1b, gw2t, lgb, gb2, 1, nullptr, nullptr, nullptr, nullptr, NB, GH_F, GH_F, 4);
  k_final<<<(NB+3)/4, 256, 0, stream>>>(latent, lgb, lw, lb, out);
}

// Round 18
// 460.255 us; speedup vs baseline: 1.0651x; 1.0651x over previous
//
#include <hip/hip_runtime.h>
#include <hip/hip_bf16.h>
#include <math.h>

#define N_NODES 50000
#define N_EDGES 800000
#define NB      512
#define IN_F    128
#define NH      4
#define HD      64
#define HDIM    256   // NH*HD
#define NG_F    200
#define GH_F    256
#define CSZ     196   // ceil(N_NODES/256)

typedef __attribute__((ext_vector_type(8))) short short8;
typedef __attribute__((ext_vector_type(8))) unsigned short u16x8;
typedef __attribute__((ext_vector_type(4))) float f32x4;
typedef __attribute__((ext_vector_type(2))) float f32x2;

static __device__ __forceinline__ float lrelu(float x){ return x > 0.f ? x : 0.2f*x; }
static __device__ __forceinline__ float fexp(float x){ return __expf(x); }

static __device__ __forceinline__ unsigned short f2b(float f){
  union { float f; unsigned int u; } v; v.f = f;
  unsigned int r = v.u + 0x7fffu + ((v.u >> 16) & 1u);
  return (unsigned short)(r >> 16);
}
static __device__ __forceinline__ float b2f(unsigned short b){
  union { unsigned int u; float f; } v; v.u = ((unsigned int)b) << 16;
  return v.f;
}
static __device__ __forceinline__ float u2f(unsigned int u){
  union { unsigned int u; float f; } v; v.u = u;
  return v.f;
}

// ---------------- fused prep A: featb conversion + g_feat pad + deg zeroing ----------------
// blocks [0,6250): featb f2b; [6250,6762): padg; [6762,6958): deg=0
__global__ __launch_bounds__(256) void k_prepa(const float* __restrict__ feat, unsigned short* __restrict__ featb,
                                               const float* __restrict__ g, unsigned short* __restrict__ gfb,
                                               int* __restrict__ deg){
  int bid = blockIdx.x;
  if (bid < 6250) {
    int i = bid*256 + threadIdx.x;                  // < N_NODES*IN_F/4
    float4 v = ((const float4*)feat)[i];
    ushort4 o;
    o.x = f2b(v.x); o.y = f2b(v.y); o.z = f2b(v.z); o.w = f2b(v.w);
    ((ushort4*)featb)[i] = o;
  } else if (bid < 6762) {
    int idx = (bid - 6250)*256 + threadIdx.x;       // < NB*256
    int b = idx >> 8, k = idx & 255;
    gfb[idx] = (k < NG_F) ? f2b(g[b*NG_F + k]) : (unsigned short)0;
  } else {
    int idx = (bid - 6762)*256 + threadIdx.x;
    if (idx < N_NODES) deg[idx] = 0;
  }
}

// ---------------- fused prep W: all 5 weight transposes (blockIdx.z selects matrix) ----------------
__global__ __launch_bounds__(256) void k_prepw(const float* __restrict__ W0, const float* __restrict__ W1,
                                               const float* __restrict__ W2, const float* __restrict__ gw1,
                                               const float* __restrict__ gw2,
                                               unsigned short* __restrict__ W0t, unsigned short* __restrict__ W1t,
                                               unsigned short* __restrict__ W2t, unsigned short* __restrict__ gw1t,
                                               unsigned short* __restrict__ gw2t){
  __shared__ unsigned short t[32][33];
  int m = blockIdx.z;
  const float* W; unsigned short* Bt; int Ksrc, Kdst, NC;
  switch (m) {
    case 0:  W = W0;  Bt = W0t;  Ksrc = IN_F; Kdst = IN_F; NC = HDIM; break;
    case 1:  W = W1;  Bt = W1t;  Ksrc = HDIM; Kdst = HDIM; NC = HDIM; break;
    case 2:  W = W2;  Bt = W2t;  Ksrc = HDIM; Kdst = HDIM; NC = HDIM; break;
    case 3:  W = gw1; Bt = gw1t; Ksrc = NG_F; Kdst = 256;  NC = GH_F; break;
    default: W = gw2; Bt = gw2t; Ksrc = GH_F; Kdst = GH_F; NC = GH_F; break;
  }
  int bn = blockIdx.x*32;
  int bk = blockIdx.y*32;
  if (bk >= Kdst || bn >= NC) return;
  int lx = threadIdx.x & 31, ly = threadIdx.x >> 5;   // 32 x 8
  #pragma unroll
  for (int i = 0; i < 32; i += 8) {
    int kr = bk + ly + i;
    t[ly+i][lx] = (kr < Ksrc) ? f2b(W[(size_t)kr*NC + bn+lx]) : (unsigned short)0;
  }
  __syncthreads();
  #pragma unroll
  for (int i = 0; i < 32; i += 8)
    Bt[(size_t)(bn+ly+i)*Kdst + bk+lx] = t[lx][ly+i];
}

// ---------------- CSR build ----------------
__global__ __launch_bounds__(256) void k_hist(const int* __restrict__ dst, int* __restrict__ deg){
  int e = blockIdx.x*256 + threadIdx.x;
  if (e < N_EDGES) atomicAdd(&deg[dst[e]], 1);
}

__global__ __launch_bounds__(64) void k_s1a(const int* __restrict__ deg, int* __restrict__ blocksum){
  int b = blockIdx.x, lane = threadIdx.x;
  int start = b*CSZ, end = min(start+CSZ, N_NODES);
  int s = 0;
  for (int i = start + lane; i < end; i += 64) s += deg[i];
  #pragma unroll
  for (int m = 1; m < 64; m <<= 1) s += __shfl_xor(s, m);
  if (lane == 0) blocksum[b] = s;
}

__global__ __launch_bounds__(256) void k_s1b(const int* __restrict__ blocksum, int* __restrict__ chunkoff){
  __shared__ int sd[256];
  int t = threadIdx.x;
  int own = blocksum[t];
  sd[t] = own; __syncthreads();
  for (int off = 1; off < 256; off <<= 1) {
    int v = (t >= off) ? sd[t-off] : 0;
    __syncthreads();
    sd[t] += v;
    __syncthreads();
  }
  chunkoff[t] = sd[t] - own;
}

__global__ __launch_bounds__(64) void k_scan2(const int* __restrict__ deg, const int* __restrict__ chunkoff,
                                              int* __restrict__ row_start, int* __restrict__ cursor){
  int b = blockIdx.x, lane = threadIdx.x;
  int start = b*CSZ, end = min(start+CSZ, N_NODES);
  int run = chunkoff[b];
  for (int k = start; k < end; k += 64) {
    int idx = k + lane;
    int v = (idx < end) ? deg[idx] : 0;
    int inc = v;
    #pragma unroll
    for (int off = 1; off < 64; off <<= 1) {
      int t = __shfl_up(inc, off);
      if (lane >= off) inc += t;
    }
    int excl = run + inc - v;
    if (idx < end) { row_start[idx] = excl; cursor[idx] = excl; }
    run += __shfl(inc, 63);
  }
  if (b == 255 && lane == 0) row_start[N_NODES] = run;
}

__global__ __launch_bounds__(256) void k_scatter(const int* __restrict__ dst, const int* __restrict__ src,
                                                 int* __restrict__ cursor, int* __restrict__ csrc){
  int e = blockIdx.x*256 + threadIdx.x;
  if (e < N_EDGES) {
    int p = atomicAdd(&cursor[dst[e]], 1);
    csrc[p] = src[e];
  }
}

// ---------------- graph segment offsets from sorted gid ----------------
__global__ __launch_bounds__(256) void k_goff(const int* __restrict__ gid, int* __restrict__ goff){
  int n = blockIdx.x*256 + threadIdx.x;
  if (n >= N_NODES) return;
  int ca = gid[n];
  if (n == 0) {
    for (int g = 0; g <= ca; g++) goff[g] = 0;
  } else {
    int pa = gid[n-1];
    for (int g = pa+1; g <= ca; g++) goff[g] = n;
  }
  if (n == N_NODES-1) {
    for (int g = ca+1; g <= NB; g++) goff[g] = N_NODES;
  }
}

// ---------------- bf16 MFMA GEMM with XCD-aware 1D grid ----------------
__global__ __launch_bounds__(256) void k_gemm_bf16(const unsigned short* __restrict__ A,
                                                   const unsigned short* __restrict__ Bt,
                                                   unsigned short* __restrict__ C,
                                                   const float* __restrict__ bias, int act,
                                                   const float* __restrict__ al, const float* __restrict__ ar,
                                                   float* __restrict__ el, float* __restrict__ er,
                                                   int M, int K, int NC, int ntiles){
  __shared__ unsigned short As[128][72];
  __shared__ unsigned short Bs[64][72];
  __shared__ float sEL[2][2][4][16];
  __shared__ float sER[2][2][4][16];
  const int bid = blockIdx.x;
  const int xcd = bid & 7;
  const int r   = bid >> 3;
  const int q   = r / ntiles;
  const int nt  = r - q*ntiles;
  const int mtile = q*8 + xcd;
  if (mtile*128 >= M) return;
  const int bm = mtile*128, bn = nt*64;
  const int tid = threadIdx.x;
  const int wid = tid >> 6, lane = tid & 63;
  const int wr = wid >> 1, wc = wid & 1;
  const int l15 = lane & 15, lg = lane >> 4;
  const int ar_ = tid >> 1, ak = (tid & 1) * 32;
  const int br = tid >> 2, bkp = (tid & 3) * 16;
  int agrow = bm + ar_; if (agrow >= M) agrow = M - 1;

  f32x4 acc[4][2] = {};
  for (int k0 = 0; k0 < K; k0 += 64) {
    #pragma unroll
    for (int p = 0; p < 4; p++)
      *(uint4*)(&As[ar_][ak + p*8]) = *(const uint4*)(A + (size_t)agrow*K + k0 + ak + p*8);
    #pragma unroll
    for (int p = 0; p < 2; p++)
      *(uint4*)(&Bs[br][bkp + p*8]) = *(const uint4*)(Bt + (size_t)(bn + br)*K + k0 + bkp + p*8);
    __syncthreads();
    #pragma unroll
    for (int ks = 0; ks < 2; ks++) {
      short8 af[4], bf[2];
      #pragma unroll
      for (int m = 0; m < 4; m++) af[m] = *(const short8*)(&As[wr*64 + m*16 + l15][ks*32 + lg*8]);
      #pragma unroll
      for (int nn = 0; nn < 2; nn++) bf[nn] = *(const short8*)(&Bs[wc*32 + nn*16 + l15][ks*32 + lg*8]);
      #pragma unroll
      for (int m = 0; m < 4; m++)
        #pragma unroll
        for (int nn = 0; nn < 2; nn++)
          acc[m][nn] = __builtin_amdgcn_mfma_f32_16x16x32_bf16(af[m], bf[nn], acc[m][nn], 0, 0, 0);
    }
    __syncthreads();
  }
  #pragma unroll
  for (int m = 0; m < 4; m++)
    #pragma unroll
    for (int nn = 0; nn < 2; nn++) {
      int col = bn + wc*32 + nn*16 + l15;
      float bv = bias ? bias[col] : 0.f;
      #pragma unroll
      for (int i = 0; i < 4; i++) {
        int row = bm + wr*64 + m*16 + lg*4 + i;
        if (row < M) {
          float v = acc[m][nn][i] + bv;
          if (act) v = fmaxf(v, 0.f);
          C[(size_t)row*NC + col] = f2b(v);
        }
      }
    }
  // fused attention-logit epilogue
  if (al) {
    int hidx = bn >> 6;
    float pl[16], pr[16];
    #pragma unroll
    for (int m = 0; m < 4; m++)
      #pragma unroll
      for (int i = 0; i < 4; i++) {
        float sl = 0.f, sr = 0.f;
        #pragma unroll
        for (int nn = 0; nn < 2; nn++) {
          int colh = wc*32 + nn*16 + l15;
          sl += acc[m][nn][i] * al[hidx*64 + colh];
          sr += acc[m][nn][i] * ar[hidx*64 + colh];
        }
        pl[m*4+i] = sl; pr[m*4+i] = sr;
      }
    #pragma unroll
    for (int k = 0; k < 16; k++) {
      #pragma unroll
      for (int mm = 1; mm < 16; mm <<= 1) {
        pl[k] += __shfl_xor(pl[k], mm);
        pr[k] += __shfl_xor(pr[k], mm);
      }
    }
    if (l15 == 0) {
      #pragma unroll
      for (int k = 0; k < 16; k++) { sEL[wr][wc][lg][k] = pl[k]; sER[wr][wc][lg][k] = pr[k]; }
    }
    __syncthreads();
    if (tid < 128) {
      int k = tid & 15;
      int lg2 = (tid >> 4) & 3;
      int wr2 = tid >> 6;
      float vl = sEL[wr2][0][lg2][k] + sEL[wr2][1][lg2][k];
      float vr = sER[wr2][0][lg2][k] + sER[wr2][1][lg2][k];
      int m = k >> 2, i = k & 3;
      int row = bm + wr2*64 + m*16 + lg2*4 + i;
      if (row < M) { el[row*NH + hidx] = vl; er[row*NH + hidx] = vr; }
    }
  }
}

// ---------------- fused single-pass edge softmax + aggregation (proven round-15 config) ----------------
__global__ __launch_bounds__(256) void k_agg(
    const unsigned short* __restrict__ f, const float* __restrict__ el, const float* __restrict__ er,
    const int* __restrict__ row_start, const int* __restrict__ csrc,
    const unsigned short* __restrict__ resid, unsigned short* __restrict__ out, int act){
  __shared__ float sA[4][64][4];
  __shared__ int   sS[4][64];
  int wid  = threadIdx.x >> 6;
  int lane = threadIdx.x & 63;
  int n = blockIdx.x*4 + wid;          // N_NODES % 4 == 0
  int half = lane >> 5;
  int c    = lane & 31;                // feature chunk: features c*8 .. c*8+7
  int h    = c >> 3;                   // head of this chunk
  int e0 = row_start[n], e1 = row_start[n+1];
  float4 erv = ((const float4*)er)[n];

  float4 den = make_float4(0.f,0.f,0.f,0.f);
  f32x2 acc2[4] = {};

  for (int base = e0; base < e1; base += 64) {
    int cnt = min(64, e1 - base);
    int   s_l = 0;
    float4 a4 = make_float4(0.f,0.f,0.f,0.f);
    if (base + lane < e1) {
      s_l = csrc[base + lane];
      float4 ev = ((const float4*)el)[s_l];
      a4.x = fexp(lrelu(ev.x + erv.x));
      a4.y = fexp(lrelu(ev.y + erv.y));
      a4.z = fexp(lrelu(ev.z + erv.z));
      a4.w = fexp(lrelu(ev.w + erv.w));
    }
    den.x += a4.x; den.y += a4.y; den.z += a4.z; den.w += a4.w;
    sS[wid][lane] = s_l;
    sA[wid][lane][0] = a4.x; sA[wid][lane][1] = a4.y;
    sA[wid][lane][2] = a4.z; sA[wid][lane][3] = a4.w;
    __builtin_amdgcn_sched_barrier(0);   // ds_writes complete before the read loop (intra-wave in-order)
    for (int j = 0; j < cnt; j += 8) {   // 8 edges = 4 pairs per superstep
      uint4 u[4]; f32x2 aa[4];
      #pragma unroll
      for (int p = 0; p < 4; p++) {
        int jj = j + 2*p + half;
        float a = 0.f; int s;
        if (jj < cnt) { s = sS[wid][jj]; a = sA[wid][jj][h]; } else { s = sS[wid][j]; }
        u[p] = *(const uint4*)(f + (size_t)s*HDIM + c*8);
        aa[p][0] = a; aa[p][1] = a;
      }
      #pragma unroll
      for (int p = 0; p < 4; p++) {
        f32x2 p0, p1, p2, p3;
        p0[0] = u2f(u[p].x << 16); p0[1] = u2f(u[p].x & 0xffff0000u);
        p1[0] = u2f(u[p].y << 16); p1[1] = u2f(u[p].y & 0xffff0000u);
        p2[0] = u2f(u[p].z << 16); p2[1] = u2f(u[p].z & 0xffff0000u);
        p3[0] = u2f(u[p].w << 16); p3[1] = u2f(u[p].w & 0xffff0000u);
        asm volatile("v_pk_fma_f32 %0, %1, %2, %0" : "+v"(acc2[0]) : "v"(p0), "v"(aa[p]));
        asm volatile("v_pk_fma_f32 %0, %1, %2, %0" : "+v"(acc2[1]) : "v"(p1), "v"(aa[p]));
        asm volatile("v_pk_fma_f32 %0, %1, %2, %0" : "+v"(acc2[2]) : "v"(p2), "v"(aa[p]));
        asm volatile("v_pk_fma_f32 %0, %1, %2, %0" : "+v"(acc2[3]) : "v"(p3), "v"(aa[p]));
      }
    }
  }
  #pragma unroll
  for (int m = 1; m < 64; m <<= 1) {
    den.x += __shfl_xor(den.x, m);
    den.y += __shfl_xor(den.y, m);
    den.z += __shfl_xor(den.z, m);
    den.w += __shfl_xor(den.w, m);
  }
  float accv[8];
  #pragma unroll
  for (int q = 0; q < 4; q++) {
    accv[2*q]   = acc2[q][0] + __shfl_xor(acc2[q][0], 32);
    accv[2*q+1] = acc2[q][1] + __shfl_xor(acc2[q][1], 32);
  }

  float d_h = h==0 ? den.x : h==1 ? den.y : h==2 ? den.z : den.w;
  float inv = d_h > 0.f ? 1.0f/d_h : 0.f;

  if (half == 0) {
    #pragma unroll
    for (int k = 0; k < 8; k++) accv[k] *= inv;
    if (resid) {
      u16x8 r = *(const u16x8*)(resid + (size_t)n*HDIM + c*8);
      #pragma unroll
      for (int k = 0; k < 8; k++) accv[k] += b2f((unsigned short)r[k]);
    }
    if (act) {
      #pragma unroll
      for (int k = 0; k < 8; k++) accv[k] = accv[k] > 0.f ? accv[k] : (fexp(accv[k]) - 1.0f);
    }
    u16x8 o;
    #pragma unroll
    for (int k = 0; k < 8; k++) o[k] = f2b(accv[k]);
    *(u16x8*)(out + (size_t)n*HDIM + c*8) = o;
  }
}

// ---------------- layer 3 projection from bf16 h ----------------
__global__ __launch_bounds__(256) void k_l3proj(const unsigned short* __restrict__ h,
    const float* __restrict__ W3, const float* __restrict__ rW3,
    const float* __restrict__ al3, const float* __restrict__ ar3,
    float* __restrict__ f3, float* __restrict__ r3,
    float* __restrict__ el3, float* __restrict__ er3){
  int n = blockIdx.x*4 + (threadIdx.x >> 6);
  int lane = threadIdx.x & 63;
  if (n >= N_NODES) return;
  ushort4 u = ((const ushort4*)(h + (size_t)n*HDIM))[lane];
  float hk[4] = {b2f(u.x), b2f(u.y), b2f(u.z), b2f(u.w)};
  const float4* w  = (const float4*)W3;
  const float4* rw = (const float4*)rW3;
  float4 acc = make_float4(0.f,0.f,0.f,0.f);
  float4 rac = make_float4(0.f,0.f,0.f,0.f);
  #pragma unroll
  for (int j = 0; j < 4; j++) {
    float4 wv = w[lane*4 + j];
    float4 rv = rw[lane*4 + j];
    acc.x += hk[j]*wv.x; acc.y += hk[j]*wv.y; acc.z += hk[j]*wv.z; acc.w += hk[j]*wv.w;
    rac.x += hk[j]*rv.x; rac.y += hk[j]*rv.y; rac.z += hk[j]*rv.z; rac.w += hk[j]*rv.w;
  }
  #pragma unroll
  for (int m = 1; m < 64; m <<= 1) {
    acc.x += __shfl_xor(acc.x, m); acc.y += __shfl_xor(acc.y, m);
    acc.z += __shfl_xor(acc.z, m); acc.w += __shfl_xor(acc.w, m);
    rac.x += __shfl_xor(rac.x, m); rac.y += __shfl_xor(rac.y, m);
    rac.z += __shfl_xor(rac.z, m); rac.w += __shfl_xor(rac.w, m);
  }
  if (lane == 0) {
    ((float4*)f3)[n] = acc;
    ((float4*)r3)[n] = rac;
    float4 e1 = make_float4(acc.x*al3[0], acc.y*al3[1], acc.z*al3[2], acc.w*al3[3]);
    float4 e2 = make_float4(acc.x*ar3[0], acc.y*ar3[1], acc.z*ar3[2], acc.w*ar3[3]);
    ((float4*)el3)[n] = e1;
    ((float4*)er3)[n] = e2;
  }
}

// ---------------- layer 3 per-node aggregation -> hn[N][4] (NO atomics) ----------------
__global__ __launch_bounds__(256) void k_l3node(
    const float* __restrict__ f3, const float* __restrict__ el3, const float* __restrict__ er3,
    const int* __restrict__ row_start, const int* __restrict__ csrc,
    const float* __restrict__ r3, float* __restrict__ hn){
  int g = threadIdx.x >> 4;
  int l = threadIdx.x & 15;
  int n = blockIdx.x*16 + g;        // N_NODES % 16 == 0
  int e0 = row_start[n], e1 = row_start[n+1];
  float4 erv = ((const float4*)er3)[n];

  float4 dn  = make_float4(0.f,0.f,0.f,0.f);
  float4 acc = make_float4(0.f,0.f,0.f,0.f);
  for (int i = e0 + l; i < e1; i += 16) {
    int s = csrc[i];
    float4 ev = ((const float4*)el3)[s];
    float ax = fexp(lrelu(ev.x + erv.x));
    float ay = fexp(lrelu(ev.y + erv.y));
    float az = fexp(lrelu(ev.z + erv.z));
    float aw = fexp(lrelu(ev.w + erv.w));
    dn.x += ax; dn.y += ay; dn.z += az; dn.w += aw;
    float4 fv = ((const float4*)f3)[s];
    acc.x += ax*fv.x; acc.y += ay*fv.y; acc.z += az*fv.z; acc.w += aw*fv.w;
  }
  #pragma unroll
  for (int m = 1; m < 16; m <<= 1) {
    dn.x += __shfl_xor(dn.x, m);  dn.y += __shfl_xor(dn.y, m);
    dn.z += __shfl_xor(dn.z, m);  dn.w += __shfl_xor(dn.w, m);
    acc.x += __shfl_xor(acc.x, m); acc.y += __shfl_xor(acc.y, m);
    acc.z += __shfl_xor(acc.z, m); acc.w += __shfl_xor(acc.w, m);
  }
  if (l == 0) {
    float4 rv = ((const float4*)r3)[n];
    float4 o;
    o.x = (dn.x > 0.f ? acc.x/dn.x : 0.f) + rv.x;
    o.y = (dn.y > 0.f ? acc.y/dn.y : 0.f) + rv.y;
    o.z = (dn.z > 0.f ? acc.z/dn.z : 0.f) + rv.z;
    o.w = (dn.w > 0.f ? acc.w/dn.w : 0.f) + rv.w;
    ((float4*)hn)[n] = o;
  }
}

// ---------------- deterministic per-graph segment sum ----------------
__global__ __launch_bounds__(64) void k_gseg(const float* __restrict__ hn, const int* __restrict__ goff,
                                             float* __restrict__ latent){
  int b = blockIdx.x;
  int lane = threadIdx.x;
  int n0 = goff[b], n1 = goff[b+1];
  float4 s = make_float4(0.f,0.f,0.f,0.f);
  for (int n = n0 + lane; n < n1; n += 64) {
    float4 v = ((const float4*)hn)[n];
    s.x += v.x; s.y += v.y; s.z += v.z; s.w += v.w;
  }
  #pragma unroll
  for (int m = 1; m < 64; m <<= 1) {
    s.x += __shfl_xor(s.x, m); s.y += __shfl_xor(s.y, m);
    s.z += __shfl_xor(s.z, m); s.w += __shfl_xor(s.w, m);
  }
  if (lane == 0) ((float4*)latent)[b] = s;
}

// ---------------- final ----------------
__global__ __launch_bounds__(256) void k_final(const float* __restrict__ latent, const unsigned short* __restrict__ lgb,
    const float* __restrict__ lw, const float* __restrict__ lb, float* __restrict__ out){
  int b = blockIdx.x*4 + (threadIdx.x >> 6);
  int lane = threadIdx.x & 63;
  if (b >= NB) return;
  ushort4 u = ((const ushort4*)(lgb + (size_t)b*GH_F))[lane];
  float4 wv = ((const float4*)(lw + NH))[lane];
  float s = b2f(u.x)*wv.x + b2f(u.y)*wv.y + b2f(u.z)*wv.z + b2f(u.w)*wv.w;
  #pragma unroll
  for (int m = 1; m < 64; m <<= 1) s += __shfl_xor(s, m);
  if (lane == 0) {
    float4 lv = ((const float4*)latent)[b];
    out[b] = s + lv.x*lw[0] + lv.y*lw[1] + lv.z*lw[2] + lv.w*lw[3] + lb[0];
  }
}

__global__ __launch_bounds__(256) void k_sentinel(float* out){
  int i = blockIdx.x*256 + threadIdx.x;
  if (i < NB) out[i] = -12345.0f;
}

extern "C" void kernel_launch(void* const* d_in, const int* in_sizes, int n_in,
                              void* d_out, int out_size, void* d_ws, size_t ws_size,
                              hipStream_t stream){
  const float* feat   = (const float*)d_in[0];
  const int*   src    = (const int*)d_in[1];
  const int*   dst    = (const int*)d_in[2];
  const int*   gid    = (const int*)d_in[3];
  const float* g_feat = (const float*)d_in[4];
  const float* W0   = (const float*)d_in[5];
  const float* al0  = (const float*)d_in[6];
  const float* ar0  = (const float*)d_in[7];
  const float* W1   = (const float*)d_in[8];
  const float* al1  = (const float*)d_in[9];
  const float* ar1  = (const float*)d_in[10];
  const float* W2   = (const float*)d_in[11];
  const float* al2  = (const float*)d_in[12];
  const float* ar2  = (const float*)d_in[13];
  const float* W3   = (const float*)d_in[14];
  const float* al3  = (const float*)d_in[15];
  const float* ar3  = (const float*)d_in[16];
  const float* rW3  = (const float*)d_in[17];
  const float* gw1  = (const float*)d_in[18];
  const float* gb1  = (const float*)d_in[19];
  const float* gw2  = (const float*)d_in[20];
  const float* gb2  = (const float*)d_in[21];
  const float* lw   = (const float*)d_in[22];
  const float* lb   = (const float*)d_in[23];
  float* out = (float*)d_out;

  char* base = (char*)d_ws;
  size_t off = 0;
  auto alloc = [&](size_t bytes)->char* {
    char* r = base + off;
    off += (bytes + 255) & ~(size_t)255;
    return r;
  };
  // bf16 buffers
  unsigned short* featb = (unsigned short*)alloc((size_t)N_NODES*IN_F*2);
  unsigned short* fbuf  = (unsigned short*)alloc((size_t)N_NODES*HDIM*2);
  unsigned short* hA    = (unsigned short*)alloc((size_t)N_NODES*HDIM*2);
  unsigned short* hB    = (unsigned short*)alloc((size_t)N_NODES*HDIM*2);
  unsigned short* W0t   = (unsigned short*)alloc((size_t)IN_F*HDIM*2);   // [HDIM][IN_F]
  unsigned short* W1t   = (unsigned short*)alloc((size_t)HDIM*HDIM*2);
  unsigned short* W2t   = (unsigned short*)alloc((size_t)HDIM*HDIM*2);
  unsigned short* gfb   = (unsigned short*)alloc((size_t)NB*256*2);      // padded g_feat
  unsigned short* gw1t  = (unsigned short*)alloc((size_t)GH_F*256*2);    // [256][256] (K padded)
  unsigned short* gw2t  = (unsigned short*)alloc((size_t)GH_F*GH_F*2);
  unsigned short* g1b   = (unsigned short*)alloc((size_t)NB*GH_F*2);
  unsigned short* lgb   = (unsigned short*)alloc((size_t)NB*GH_F*2);
  // fp32 small buffers
  float* el   = (float*)alloc((size_t)N_NODES*NH*4);
  float* er   = (float*)alloc((size_t)N_NODES*NH*4);
  float* f3   = (float*)alloc((size_t)N_NODES*NH*4);
  float* r3   = (float*)alloc((size_t)N_NODES*NH*4);
  float* hn   = (float*)alloc((size_t)N_NODES*NH*4);
  int* deg       = (int*)alloc((size_t)N_NODES*4);
  int* row_start = (int*)alloc((size_t)(N_NODES+1)*4);
  int* cursor    = (int*)alloc((size_t)N_NODES*4);
  int* csrc      = (int*)alloc((size_t)N_EDGES*4);
  int* blocksum  = (int*)alloc(256*4);
  int* chunkoff  = (int*)alloc(256*4);
  int* goff      = (int*)alloc((size_t)(NB+1)*4);
  float* latent  = (float*)alloc((size_t)NB*NH*4);

  if (off > ws_size) {
    k_sentinel<<<2, 256, 0, stream>>>(out);
    return;
  }

  // fused prep: featb + padded g_feat + deg zeroing; all 5 weight transposes in one launch
  k_prepa<<<6958, 256, 0, stream>>>(feat, featb, g_feat, gfb, deg);
  {
    dim3 gw(8, 8, 5);
    k_prepw<<<gw, 256, 0, stream>>>(W0, W1, W2, gw1, gw2, W0t, W1t, W2t, gw1t, gw2t);
  }

  // CSR build (shared by all 4 layers) + graph offsets — parallel 3-stage scan
  k_hist<<<(N_EDGES+255)/256, 256, 0, stream>>>(dst, deg);
  k_s1a<<<256, 64, 0, stream>>>(deg, blocksum);
  k_s1b<<<1, 256, 0, stream>>>(blocksum, chunkoff);
  k_scan2<<<256, 64, 0, stream>>>(deg, chunkoff, row_start, cursor);
  k_scatter<<<(N_EDGES+255)/256, 256, 0, stream>>>(dst, src, cursor, csrc);
  k_goff<<<(N_NODES+255)/256, 256, 0, stream>>>(gid, goff);

  // XCD-aware 1D grids
  const int mt_main = (N_NODES + 127) / 128;                 // 391
  const int grid_main = 8 * ((mt_main + 7) / 8) * 4;         // 1568
  const int mt_mlp = (NB + 127) / 128;                       // 4
  const int grid_mlp = 8 * ((mt_mlp + 7) / 8) * 4;           // 32

  // Layer 0 (GEMM with fused logits)
  k_gemm_bf16<<<grid_main, 256, 0, stream>>>(featb, W0t, fbuf, nullptr, 0, al0, ar0, el, er, N_NODES, IN_F, HDIM, 4);
  k_agg<<<N_NODES/4, 256, 0, stream>>>(fbuf, el, er, row_start, csrc, nullptr, hA, 1);

  // Layer 1
  k_gemm_bf16<<<grid_main, 256, 0, stream>>>(hA, W1t, fbuf, nullptr, 0, al1, ar1, el, er, N_NODES, HDIM, HDIM, 4);
  k_agg<<<N_NODES/4, 256, 0, stream>>>(fbuf, el, er, row_start, csrc, hA, hB, 1);

  // Layer 2
  k_gemm_bf16<<<grid_main, 256, 0, stream>>>(hB, W2t, fbuf, nullptr, 0, al2, ar2, el, er, N_NODES, HDIM, HDIM, 4);
  k_agg<<<N_NODES/4, 256, 0, stream>>>(fbuf, el, er, row_start, csrc, hB, hA, 1);

  // Layer 3 (C=1): per-node output then deterministic per-graph segment sum
  k_l3proj<<<(N_NODES+3)/4, 256, 0, stream>>>(hA, W3, rW3, al3, ar3, f3, r3, el, er);
  k_l3node<<<N_NODES/16, 256, 0, stream>>>(f3, el, er, row_start, csrc, r3, hn);
  k_gseg<<<NB, 64, 0, stream>>>(hn, goff, latent);

  // Graph MLP via MFMA GEMM (K padded to 256) + final
  k_gemm_bf16<<<grid_mlp, 256, 0, stream>>>(gfb, gw1t, g1b, gb1, 1, nullptr, nullptr, nullptr, nullptr, NB, 256, GH_F, 4);
  k_gemm_bf16<<<grid_mlp, 256, 0, stream>>>(g1b, gw2t, lgb, gb2, 1, nullptr, nullptr, nullptr, nullptr, NB, GH_F, GH_F, 4);
  k_final<<<(NB+3)/4, 256, 0, stream>>>(latent, lgb, lw, lb, out);
}